// Round 1
// baseline (1189.048 us; speedup 1.0000x reference)
//
#include <hip/hip_runtime.h>
#include <math.h>

#define BATCH 2048
#define C 64
#define S 96
#define NB 10
#define L 1023
#define BC (BATCH * C)       // 131072
#define RB 4                 // batch rows per compute workgroup
#define TOTAL ((unsigned)BC * (unsigned)L)  // 134,086,656

// ---------------------------------------------------------------------------
// Kernel 1: the sequential WaveNet chain. One workgroup = RB batch rows.
// Thread (r, c) owns element (b0+r, c) of `current`.
// Writes: curcols[i][b][c] (entry-value of current at block i), d_out[0:4096].
// ---------------------------------------------------------------------------
__global__ __launch_bounds__(256)
void wn_compute(const float* __restrict__ x, const float* __restrict__ buf,
                const float* __restrict__ inp_w, const float* __restrict__ inp_b,
                const float* __restrict__ fw0, const float* __restrict__ fw1,
                const float* __restrict__ fb,
                const float* __restrict__ gw0, const float* __restrict__ gw1,
                const float* __restrict__ gb,
                const float* __restrict__ rw, const float* __restrict__ rb,
                const float* __restrict__ sw, const float* __restrict__ sb,
                const float* __restrict__ h1w, const float* __restrict__ h1b,
                const float* __restrict__ h2w, const float* __restrict__ h2b,
                float* __restrict__ out, float* __restrict__ curcols)
{
    __shared__ float cur_lds[RB][C];
    __shared__ float del_lds[RB][C];
    __shared__ float z_lds[RB][C];
    __shared__ float skip_lds[RB][S];
    __shared__ float h2_lds[RB][S];
    __shared__ float x_lds[RB][32];

    const int tid = threadIdx.x;
    const int r   = tid >> 6;
    const int c   = tid & 63;
    const int b0  = blockIdx.x * RB;
    const int row = (b0 + r) * C + c;   // flat (b, c)

    // stage x rows for this tile
    if (tid < RB * 32)
        x_lds[tid >> 5][tid & 31] = x[(b0 + (tid >> 5)) * 32 + (tid & 31)];
    for (int idx = tid; idx < RB * S; idx += 256)
        skip_lds[idx / S][idx % S] = 0.0f;

    // prefetch all 10 delayed values (column 2^i - 1 of this row's buffer)
    float dly[NB];
    const int offs[NB] = {0, 1, 3, 7, 15, 31, 63, 127, 255, 511};
#pragma unroll
    for (int i = 0; i < NB; i++)
        dly[i] = buf[(size_t)row * L + offs[i]];

    __syncthreads();

    // current = x @ inp_w.T + inp_b
    float cur = inp_b[c];
    {
        const float4* wr = (const float4*)(inp_w + c * 32);
        const float4* xr = (const float4*)(&x_lds[r][0]);
#pragma unroll
        for (int q = 0; q < 8; q++) {
            float4 w = wr[q], xv = xr[q];
            cur = fmaf(w.x, xv.x, cur); cur = fmaf(w.y, xv.y, cur);
            cur = fmaf(w.z, xv.z, cur); cur = fmaf(w.w, xv.w, cur);
        }
    }

    for (int i = 0; i < NB; i++) {
        // entry value of current goes to the buffer's block-i slot (via scratch)
        curcols[(size_t)i * BC + row] = cur;

        __syncthreads();                       // prev iter's LDS reads done
        cur_lds[r][c] = cur;
        del_lds[r][c] = dly[i];
        __syncthreads();

        // f, g = delayed @ w0.T + current @ w1.T + b
        float f = fb[i * C + c], g = gb[i * C + c];
        {
            const size_t wo = (size_t)(i * C + c) * C;
            const float4* w0 = (const float4*)(fw0 + wo);
            const float4* w1 = (const float4*)(fw1 + wo);
            const float4* w2 = (const float4*)(gw0 + wo);
            const float4* w3 = (const float4*)(gw1 + wo);
            const float4* dl = (const float4*)(&del_lds[r][0]);
            const float4* cl = (const float4*)(&cur_lds[r][0]);
#pragma unroll
            for (int q = 0; q < 16; q++) {
                float4 d4 = dl[q], c4 = cl[q];
                float4 a = w0[q], b4 = w1[q], e = w2[q], h = w3[q];
                f = fmaf(d4.x, a.x, f);  f = fmaf(d4.y, a.y, f);
                f = fmaf(d4.z, a.z, f);  f = fmaf(d4.w, a.w, f);
                f = fmaf(c4.x, b4.x, f); f = fmaf(c4.y, b4.y, f);
                f = fmaf(c4.z, b4.z, f); f = fmaf(c4.w, b4.w, f);
                g = fmaf(d4.x, e.x, g);  g = fmaf(d4.y, e.y, g);
                g = fmaf(d4.z, e.z, g);  g = fmaf(d4.w, e.w, g);
                g = fmaf(c4.x, h.x, g);  g = fmaf(c4.y, h.y, g);
                g = fmaf(c4.z, h.z, g);  g = fmaf(c4.w, h.w, g);
            }
        }
        float z = tanhf(f) * (1.0f / (1.0f + __expf(-g)));
        z_lds[r][c] = z;
        __syncthreads();

        // res = z @ rw.T + rb   (thread-local output channel c)
        float res = rb[i * C + c];
        {
            const float4* w  = (const float4*)(rw + (size_t)(i * C + c) * C);
            const float4* zl = (const float4*)(&z_lds[r][0]);
#pragma unroll
            for (int q = 0; q < 16; q++) {
                float4 a = w[q], zv = zl[q];
                res = fmaf(zv.x, a.x, res); res = fmaf(zv.y, a.y, res);
                res = fmaf(zv.z, a.z, res); res = fmaf(zv.w, a.w, res);
            }
        }

        // skip_sum += z @ sw.T + sb   (re-map threads to (row, s) items)
        for (int idx = tid; idx < RB * S; idx += 256) {
            int rr = idx / S, ss = idx % S;
            float acc = sb[i * S + ss];
            const float4* w  = (const float4*)(sw + (size_t)(i * S + ss) * C);
            const float4* zv = (const float4*)(&z_lds[rr][0]);
#pragma unroll
            for (int q = 0; q < 16; q++) {
                float4 a = w[q], zz = zv[q];
                acc = fmaf(zz.x, a.x, acc); acc = fmaf(zz.y, a.y, acc);
                acc = fmaf(zz.z, a.z, acc); acc = fmaf(zz.w, a.w, acc);
            }
            skip_lds[rr][ss] += acc;
        }

        cur = fmaf(0.3f, res, cur);
    }
    __syncthreads();

    // h = relu(skip_sum)
    for (int idx = tid; idx < RB * S; idx += 256) {
        int rr = idx / S, ss = idx % S;
        skip_lds[rr][ss] = fmaxf(skip_lds[rr][ss], 0.0f);
    }
    __syncthreads();

    // h2 = relu(h @ head1_w.T + head1_b)
    for (int idx = tid; idx < RB * S; idx += 256) {
        int rr = idx / S, ss = idx % S;
        float acc = h1b[ss];
        const float4* w  = (const float4*)(h1w + ss * S);
        const float4* hv = (const float4*)(&skip_lds[rr][0]);
#pragma unroll
        for (int q = 0; q < 24; q++) {
            float4 a = w[q], h4 = hv[q];
            acc = fmaf(h4.x, a.x, acc); acc = fmaf(h4.y, a.y, acc);
            acc = fmaf(h4.z, a.z, acc); acc = fmaf(h4.w, a.w, acc);
        }
        h2_lds[rr][ss] = fmaxf(acc, 0.0f);
    }
    __syncthreads();

    // out = h2 @ head2_w.T + head2_b   (2 outputs per row)
    if (tid < RB * 2) {
        int rr = tid >> 1, k = tid & 1;
        float acc = h2b[k];
        const float4* w  = (const float4*)(h2w + k * S);
        const float4* hv = (const float4*)(&h2_lds[rr][0]);
#pragma unroll
        for (int q = 0; q < 24; q++) {
            float4 a = w[q], h4 = hv[q];
            acc = fmaf(h4.x, a.x, acc); acc = fmaf(h4.y, a.y, acc);
            acc = fmaf(h4.z, a.z, acc); acc = fmaf(h4.w, a.w, acc);
        }
        out[(b0 + rr) * 2 + k] = acc;
    }
}

// ---------------------------------------------------------------------------
// Kernel 2: new_buf[n] = buf[n+1] flat shift, except the 10 special columns
// per row (kd+2 == power of two) which take current_i from the scratch.
// Aligned float4 stores; aligned float4 + 1 scalar on the load side.
// ---------------------------------------------------------------------------
__global__ __launch_bounds__(256)
void wn_copy(const float* __restrict__ buf, const float* __restrict__ curcols,
             float* __restrict__ nb)
{
    const unsigned total4 = TOTAL >> 2;          // 33,521,664
    const unsigned stride = gridDim.x * blockDim.x;
    for (unsigned t = blockIdx.x * 256u + threadIdx.x; t < total4; t += stride) {
        const unsigned g0 = t << 2;
        float4 q = *(const float4*)(buf + g0);               // buf[g0 .. g0+3]
        float s4 = (g0 + 4u < TOTAL) ? buf[g0 + 4u] : 0.0f;  // buf[g0+4]
        float v[4] = {q.y, q.z, q.w, s4};                    // shifted by +1

        unsigned row0 = g0 / L;
        unsigned kd0  = g0 - row0 * L;
#pragma unroll
        for (int j = 0; j < 4; j++) {
            unsigned kd = kd0 + (unsigned)j;
            unsigned rr = row0;
            if (kd >= L) { kd -= L; rr++; }
            if (((kd + 2u) & (kd + 1u)) == 0u) {             // kd+2 = 2^(i+1)
                int i = (31 - __clz((int)(kd + 2u))) - 1;
                v[j] = curcols[(size_t)i * BC + rr];
            }
        }
        *(float4*)(nb + g0) = make_float4(v[0], v[1], v[2], v[3]);
    }
}

extern "C" void kernel_launch(void* const* d_in, const int* in_sizes, int n_in,
                              void* d_out, int out_size, void* d_ws, size_t ws_size,
                              hipStream_t stream)
{
    const float* x     = (const float*)d_in[0];
    const float* buf   = (const float*)d_in[1];
    const float* inp_w = (const float*)d_in[2];
    const float* inp_b = (const float*)d_in[3];
    const float* fw0   = (const float*)d_in[4];
    const float* fw1   = (const float*)d_in[5];
    const float* fb    = (const float*)d_in[6];
    const float* gw0   = (const float*)d_in[7];
    const float* gw1   = (const float*)d_in[8];
    const float* gb    = (const float*)d_in[9];
    const float* rw    = (const float*)d_in[10];
    const float* rb    = (const float*)d_in[11];
    const float* sw    = (const float*)d_in[12];
    const float* sb    = (const float*)d_in[13];
    const float* h1w   = (const float*)d_in[14];
    const float* h1b   = (const float*)d_in[15];
    const float* h2w   = (const float*)d_in[16];
    const float* h2b   = (const float*)d_in[17];

    float* out     = (float*)d_out;                       // (2048, 2)
    float* nb      = (float*)d_out + (size_t)BATCH * 2;   // (2048, 64, 1023)
    float* curcols = (float*)d_ws;                        // (10, 2048, 64)

    wn_compute<<<dim3(BATCH / RB), dim3(256), 0, stream>>>(
        x, buf, inp_w, inp_b, fw0, fw1, fb, gw0, gw1, gb,
        rw, rb, sw, sb, h1w, h1b, h2w, h2b, out, curcols);

    wn_copy<<<dim3(4096), dim3(256), 0, stream>>>(buf, curcols, nb);
}